// Round 8
// baseline (541.088 us; speedup 1.0000x reference)
//
#include <hip/hip_runtime.h>
#include <hip/hip_bf16.h>

// RGCN: N=100000, F=128, R=4, E=1600000, L=2.
// R8 = R7 with (a) fill_edges replaced by a binned two-pass scatter
// (chunk-reserved coalesced pair write, then L2-local per-bin fill) and
// (b) transform writing only the live output per layer (f32 XOR bf16).
#define N_NODES 100000
#define FDIM 128
#define RREL 4
#define NEDGE 1600000
#define NSEG (N_NODES * RREL)          // 400000
#define SCAN_NB ((NSEG + 1023) / 1024) // 391
#define KB_TOT 20                      // 640 / 32 k-steps
#define BSW_PER_LAYER (KB_TOT * 8 * 64 * 8) // 81920 bf16 elems = 160 KB
#define BIN_SHIFT 12                   // 4096 segs per bin
#define NBINS 98                       // ceil(400000/4096)
#define EPB 16384                      // edges per bin_scatter block

typedef __attribute__((ext_vector_type(8))) short bfrag; // 8 bf16 (4 VGPR)
typedef __attribute__((ext_vector_type(4))) float ffrag; // 4 f32 acc

__device__ __forceinline__ unsigned short f2bf(float f) {
    unsigned u = __float_as_uint(f);
    u += 0x7fffu + ((u >> 16) & 1u); // RNE
    return (unsigned short)(u >> 16);
}
__device__ __forceinline__ float bf_lo(unsigned u) { return __uint_as_float(u << 16); }
__device__ __forceinline__ float bf_hi(unsigned u) { return __uint_as_float(u & 0xffff0000u); }

// ---------- cast x (f32) -> bf16 sidecar ----------
__global__ __launch_bounds__(256) void cast_x(
    const float* __restrict__ x, unsigned short* __restrict__ xb)
{
    int i = blockIdx.x * 256 + threadIdx.x;
    float4 v = ((const float4*)x)[i];
    ushort4 o = { f2bf(v.x), f2bf(v.y), f2bf(v.z), f2bf(v.w) };
    ((ushort4*)xb)[i] = o;
}

// ---------- pre-swizzle weights into MFMA B-fragment order ----------
__global__ __launch_bounds__(256) void prep_weights(
    const float* __restrict__ W,    // [L,4,128,128]
    const float* __restrict__ root, // [L,128,128]
    unsigned short* __restrict__ Bsw)
{
    int idx = blockIdx.x * 256 + threadIdx.x;
    int layer = idx / BSW_PER_LAYER;
    int rem = idx % BSW_PER_LAYER;
    int kb = rem / 4096;
    int rem2 = rem % 4096;
    int ct = rem2 / 512;
    int rem3 = rem2 % 512;
    int lane = rem3 / 8;
    int j = rem3 % 8;
    int k = kb * 32 + (lane >> 4) * 8 + j;
    int n = ct * 16 + (lane & 15);
    float v;
    if (k < 512) v = W[(size_t)layer * 4 * 128 * 128 + (size_t)k * 128 + n];
    else         v = root[(size_t)layer * 128 * 128 + (size_t)(k - 512) * 128 + n];
    Bsw[idx] = f2bf(v);
}

// ---------- CSR build: counts + scan (verbatim) ----------
__global__ __launch_bounds__(256) void count_edges(
    const int* __restrict__ dst, const int* __restrict__ et,
    int* __restrict__ counts)
{
    int e = blockIdx.x * 256 + threadIdx.x;
    if (e < NEDGE) atomicAdd(&counts[dst[e] * RREL + et[e]], 1);
}

__global__ __launch_bounds__(256) void scan_blocks(
    const int* __restrict__ counts, int* __restrict__ cursor,
    int* __restrict__ blockSums)
{
    __shared__ int waveTot[4];
    int base = blockIdx.x * 1024 + threadIdx.x * 4;
    int v[4];
    #pragma unroll
    for (int i = 0; i < 4; ++i) {
        int idx = base + i;
        v[i] = (idx < NSEG) ? counts[idx] : 0;
    }
    int tsum = v[0] + v[1] + v[2] + v[3];
    int lane = threadIdx.x & 63;
    int wave = threadIdx.x >> 6;
    int inc = tsum;
    #pragma unroll
    for (int d = 1; d < 64; d <<= 1) {
        int o = __shfl_up(inc, d, 64);
        if (lane >= d) inc += o;
    }
    if (lane == 63) waveTot[wave] = inc;
    __syncthreads();
    int wbase = 0;
    for (int w = 0; w < wave; ++w) wbase += waveTot[w];
    int run = wbase + inc - tsum;
    #pragma unroll
    for (int i = 0; i < 4; ++i) {
        int idx = base + i;
        if (idx < NSEG) cursor[idx] = run;
        run += v[i];
    }
    if (threadIdx.x == 255) blockSums[blockIdx.x] = wbase + inc;
}

__global__ __launch_bounds__(512) void scan_partials(int* __restrict__ blockSums)
{
    __shared__ int sm[512];
    int t = threadIdx.x;
    int v = (t < SCAN_NB) ? blockSums[t] : 0;
    sm[t] = v;
    __syncthreads();
    for (int d = 1; d < 512; d <<= 1) {
        int o = (t >= d) ? sm[t - d] : 0;
        __syncthreads();
        sm[t] += o;
        __syncthreads();
    }
    if (t < SCAN_NB) blockSums[t] = sm[t] - v;
}

__global__ __launch_bounds__(256) void scan_add(
    int* __restrict__ cursor, const int* __restrict__ blockSums)
{
    int base = blockIdx.x * 1024 + threadIdx.x * 4;
    int add = blockSums[blockIdx.x];
    #pragma unroll
    for (int i = 0; i < 4; ++i)
        if (base + i < NSEG) cursor[base + i] += add;
}

// ---------- binned fill, pass 0: snapshot bin bases from scanned cursor ----------
__global__ __launch_bounds__(128) void init_bins(
    const int* __restrict__ cursor, int* __restrict__ binCursor,
    int* __restrict__ binStart)
{
    int b = threadIdx.x;
    if (b < NBINS) {
        int sgi = b << BIN_SHIFT;
        int v = (sgi < NSEG) ? cursor[sgi] : NEDGE;
        binCursor[b] = v;
        binStart[b] = v;
    }
}

// ---------- binned fill, pass 1: chunk-reserved coalesced pair scatter ----------
// Each block: LDS histogram of its 16K edges by bin, one global atomicAdd per
// bin to reserve a contiguous chunk, then write (src,seg) pairs into chunks.
__global__ __launch_bounds__(256) void bin_scatter(
    const int* __restrict__ src, const int* __restrict__ dst,
    const int* __restrict__ et, int* __restrict__ binCursor,
    uint2* __restrict__ pairs)
{
    __shared__ int hist[NBINS];
    __shared__ int base[NBINS];
    int tid = threadIdx.x;
    for (int b = tid; b < NBINS; b += 256) hist[b] = 0;
    __syncthreads();
    int e0 = blockIdx.x * EPB;
    #pragma unroll 4
    for (int i = 0; i < EPB / 256; ++i) {
        int e = e0 + i * 256 + tid;
        if (e < NEDGE) atomicAdd(&hist[(dst[e] * RREL + et[e]) >> BIN_SHIFT], 1);
    }
    __syncthreads();
    for (int b = tid; b < NBINS; b += 256) {
        int h = hist[b];
        base[b] = h ? atomicAdd(&binCursor[b], h) : 0;
        hist[b] = 0; // reuse as local arrival cursor
    }
    __syncthreads();
    #pragma unroll 4
    for (int i = 0; i < EPB / 256; ++i) {
        int e = e0 + i * 256 + tid;
        if (e < NEDGE) {
            int seg = dst[e] * RREL + et[e];
            int b = seg >> BIN_SHIFT;
            int li = atomicAdd(&hist[b], 1);
            pairs[base[b] + li] = make_uint2((unsigned)src[e], (unsigned)seg);
        }
    }
}

// ---------- binned fill, pass 2: L2-local per-bin segment placement ----------
// One block per bin: cursor atomics + esrc scatter confined to this bin's
// 16KB cursor / 64KB esrc region (full-line assembly in one XCD's L2).
__global__ __launch_bounds__(256) void bin_fill(
    const uint2* __restrict__ pairs, const int* __restrict__ binStart,
    const int* __restrict__ binEnd, int* __restrict__ cursor,
    int* __restrict__ esrc)
{
    int b = blockIdx.x;
    int s = binStart[b], e = binEnd[b];
    for (int i = s + threadIdx.x; i < e; i += 256) {
        uint2 p = pairs[i];
        int pos = atomicAdd(&cursor[p.y], 1);
        esrc[pos] = (int)p.x;
    }
}

// ---------- per-segment gather-reduce, 16 lanes/segment (verbatim R6/R7) ----------
__global__ __launch_bounds__(256) void rgcn_aggregate(
    const unsigned short* __restrict__ xb, const int* __restrict__ esrc,
    const int* __restrict__ cursor, const int* __restrict__ counts,
    unsigned short* __restrict__ meanb)
{
    int sub = threadIdx.x >> 4;
    int lane16 = threadIdx.x & 15;
    int seg = blockIdx.x * 16 + sub;
    int end = cursor[seg];
    int c = counts[seg];
    int j = end - c;
    float acc[8] = {};
    for (; j + 1 < end; j += 2) {
        int s0 = esrc[j], s1 = esrc[j + 1];
        uint4 u0 = ((const uint4*)(xb + (size_t)s0 * FDIM))[lane16];
        uint4 u1 = ((const uint4*)(xb + (size_t)s1 * FDIM))[lane16];
        acc[0] += bf_lo(u0.x) + bf_lo(u1.x);
        acc[1] += bf_hi(u0.x) + bf_hi(u1.x);
        acc[2] += bf_lo(u0.y) + bf_lo(u1.y);
        acc[3] += bf_hi(u0.y) + bf_hi(u1.y);
        acc[4] += bf_lo(u0.z) + bf_lo(u1.z);
        acc[5] += bf_hi(u0.z) + bf_hi(u1.z);
        acc[6] += bf_lo(u0.w) + bf_lo(u1.w);
        acc[7] += bf_hi(u0.w) + bf_hi(u1.w);
    }
    if (j < end) {
        int s = esrc[j];
        uint4 u = ((const uint4*)(xb + (size_t)s * FDIM))[lane16];
        acc[0] += bf_lo(u.x); acc[1] += bf_hi(u.x);
        acc[2] += bf_lo(u.y); acc[3] += bf_hi(u.y);
        acc[4] += bf_lo(u.z); acc[5] += bf_hi(u.z);
        acc[6] += bf_lo(u.w); acc[7] += bf_hi(u.w);
    }
    float inv = 1.0f / fmaxf((float)c, 1.0f);
    uint4 o;
    o.x = (unsigned)f2bf(acc[0] * inv) | ((unsigned)f2bf(acc[1] * inv) << 16);
    o.y = (unsigned)f2bf(acc[2] * inv) | ((unsigned)f2bf(acc[3] * inv) << 16);
    o.z = (unsigned)f2bf(acc[4] * inv) | ((unsigned)f2bf(acc[5] * inv) << 16);
    o.w = (unsigned)f2bf(acc[6] * inv) | ((unsigned)f2bf(acc[7] * inv) << 16);
    ((uint4*)(meanb + (size_t)seg * FDIM))[lane16] = o;
}

// ---------- MFMA transform (R7 structure, single live output per layer) ----------
__global__ __launch_bounds__(256, 2) void rgcn_transform(
    const unsigned short* __restrict__ xb,    // [N,128] bf16 activations
    const unsigned short* __restrict__ meanb, // [N,512] bf16
    const unsigned short* __restrict__ Bsw,   // this layer's [20][8][64][8]
    const float* __restrict__ bias,           // [128]
    float* __restrict__ out,                  // [N,128] f32 (live iff writeF32)
    unsigned short* __restrict__ xbn,         // [N,128] bf16 (live iff !writeF32)
    const int writeF32)
{
    __shared__ __align__(16) unsigned char Bsm[2][8192];

    int tid = threadIdx.x;
    int wave = tid >> 6, lane = tid & 63;
    int quad = lane >> 4, rlo = lane & 15;
    int n0 = blockIdx.x * 128 + wave * 32;
    int r0 = n0 + rlo;
    int r1 = n0 + 16 + rlo;
    int r0c = min(r0, N_NODES - 1);
    int r1c = min(r1, N_NODES - 1);

    const bfrag* m0 = (const bfrag*)(meanb + (size_t)r0c * 512) + quad;
    const bfrag* m1 = (const bfrag*)(meanb + (size_t)r1c * 512) + quad;
    const bfrag* x0 = (const bfrag*)(xb + (size_t)r0c * FDIM) + quad;
    const bfrag* x1 = (const bfrag*)(xb + (size_t)r1c * FDIM) + quad;

    const uint4* gB = (const uint4*)Bsw;
    #define STAGE_B(kb, buf) do { \
        uint4* _s = (uint4*)Bsm[buf]; \
        const uint4* _g = gB + (kb) * 512; \
        _s[tid] = _g[tid]; \
        _s[tid + 256] = _g[tid + 256]; \
    } while (0)

    #define AFRAG(row, kb) ((kb) < 16 ? row##_m[(kb) * 4] : row##_x[((kb) - 16) * 4])
    const bfrag* r0_m = m0; const bfrag* r0_x = x0;
    const bfrag* r1_m = m1; const bfrag* r1_x = x1;

    ffrag acc[2][8] = {};

    STAGE_B(0, 0);
    bfrag a0p0 = AFRAG(r0, 0), a1p0 = AFRAG(r1, 0);
    bfrag a0p1 = AFRAG(r0, 1), a1p1 = AFRAG(r1, 1);
    __syncthreads();

    #pragma unroll
    for (int kb = 0; kb < KB_TOT; ++kb) {
        int cur = kb & 1;
        if (kb + 1 < KB_TOT) STAGE_B(kb + 1, cur ^ 1);

        bfrag a0 = cur ? a0p1 : a0p0;
        bfrag a1 = cur ? a1p1 : a1p0;
        if (kb + 2 < KB_TOT) {
            if (cur) { a0p1 = AFRAG(r0, kb + 2); a1p1 = AFRAG(r1, kb + 2); }
            else     { a0p0 = AFRAG(r0, kb + 2); a1p0 = AFRAG(r1, kb + 2); }
        }

        #pragma unroll
        for (int ct = 0; ct < 8; ++ct) {
            bfrag b = *(const bfrag*)&Bsm[cur][ct * 1024 + lane * 16];
            acc[0][ct] = __builtin_amdgcn_mfma_f32_16x16x32_bf16(a0, b, acc[0][ct], 0, 0, 0);
            acc[1][ct] = __builtin_amdgcn_mfma_f32_16x16x32_bf16(a1, b, acc[1][ct], 0, 0, 0);
        }
        __syncthreads();
    }
    #undef STAGE_B
    #undef AFRAG

    float bcol[8];
    #pragma unroll
    for (int ct = 0; ct < 8; ++ct) bcol[ct] = bias[ct * 16 + rlo];

    #pragma unroll
    for (int rt = 0; rt < 2; ++rt) {
        int rbase = n0 + rt * 16 + quad * 4;
        #pragma unroll
        for (int i = 0; i < 4; ++i) {
            int r = rbase + i;
            if (r < N_NODES) {
                #pragma unroll
                for (int ct = 0; ct < 8; ++ct) {
                    float v = fmaxf(acc[rt][ct][i] + bcol[ct], 0.0f);
                    int col = ct * 16 + rlo;
                    if (writeF32) out[(size_t)r * FDIM + col] = v;
                    else          xbn[(size_t)r * FDIM + col] = f2bf(v);
                }
            }
        }
    }
}

extern "C" void kernel_launch(void* const* d_in, const int* in_sizes, int n_in,
                              void* d_out, int out_size, void* d_ws, size_t ws_size,
                              hipStream_t stream) {
    const float* x        = (const float*)d_in[0];
    const int* edge_index = (const int*)d_in[1]; // [2,E]
    const int* edge_type  = (const int*)d_in[2]; // [E]
    const float* weights  = (const float*)d_in[3]; // [L,R,F,F]
    const float* roots    = (const float*)d_in[4]; // [L,F,F]
    const float* biases   = (const float*)d_in[5]; // [L,F]
    float* out = (float*)d_out;

    // workspace layout
    unsigned short* meanb = (unsigned short*)d_ws;            // NSEG*128 bf16 = 102.4 MB
    unsigned short* xb0   = meanb + (size_t)NSEG * FDIM;      // N*128 bf16
    unsigned short* xb1   = xb0 + (size_t)N_NODES * FDIM;     // N*128 bf16
    unsigned short* Bsw   = xb1 + (size_t)N_NODES * FDIM;     // 2*81920 bf16
    int* esrc   = (int*)(Bsw + 2 * BSW_PER_LAYER);            // E ints
    int* counts = esrc + NEDGE;                               // NSEG
    int* cursor = counts + NSEG;                              // NSEG
    int* blockSums = cursor + NSEG;                           // 512
    int* binCursor = blockSums + 512;                         // NBINS
    int* binStart  = binCursor + NBINS;                       // NBINS
    uint2* pairs = (uint2*)(((size_t)(binStart + NBINS) + 15) & ~(size_t)15); // E uint2 = 12.8 MB

    const int* src = edge_index;
    const int* dst = edge_index + NEDGE;

    // prep: bf16 cast + weight swizzle + CSR counts/scan (edges layer-invariant)
    cast_x<<<(N_NODES * FDIM / 4) / 256, 256, 0, stream>>>(x, xb0);
    prep_weights<<<2 * BSW_PER_LAYER / 256, 256, 0, stream>>>(weights, roots, Bsw);
    hipMemsetAsync(counts, 0, NSEG * sizeof(int), stream);
    count_edges<<<NEDGE / 256, 256, 0, stream>>>(dst, edge_type, counts);
    scan_blocks<<<SCAN_NB, 256, 0, stream>>>(counts, cursor, blockSums);
    scan_partials<<<1, 512, 0, stream>>>(blockSums);
    scan_add<<<SCAN_NB, 256, 0, stream>>>(cursor, blockSums);
    // binned two-pass fill (replaces fill_edges)
    init_bins<<<1, 128, 0, stream>>>(cursor, binCursor, binStart);
    bin_scatter<<<(NEDGE + EPB - 1) / EPB, 256, 0, stream>>>(src, dst, edge_type,
                                                             binCursor, pairs);
    bin_fill<<<NBINS, 256, 0, stream>>>(pairs, binStart, binCursor, cursor, esrc);

    const int tgrid = (N_NODES + 127) / 128; // 782

    // layer 1: bf16 sidecar only
    rgcn_aggregate<<<NSEG / 16, 256, 0, stream>>>(xb0, esrc, cursor, counts, meanb);
    rgcn_transform<<<tgrid, 256, 0, stream>>>(xb0, meanb, Bsw, biases, out, xb1, 0);
    // layer 2: f32 output only
    rgcn_aggregate<<<NSEG / 16, 256, 0, stream>>>(xb1, esrc, cursor, counts, meanb);
    rgcn_transform<<<tgrid, 256, 0, stream>>>(xb1, meanb, Bsw + BSW_PER_LAYER,
                                              biases + FDIM, out, xb0, 1);
}

// Round 9
// 476.735 us; speedup vs baseline: 1.1350x; 1.1350x over previous
//
#include <hip/hip_runtime.h>
#include <hip/hip_bf16.h>

// RGCN: N=100000, F=128, R=4, E=1600000, L=2.
// R9 = R8 with the binned fill given real parallelism:
//  - bin_scatter: EPB 2048 (grid 782, was 98)
//  - bin_fill: 1024 threads/block + LDS segment cursors (no global cursor
//    mutation); aggregate switched to start-based indexing.
#define N_NODES 100000
#define FDIM 128
#define RREL 4
#define NEDGE 1600000
#define NSEG (N_NODES * RREL)          // 400000
#define SCAN_NB ((NSEG + 1023) / 1024) // 391
#define KB_TOT 20                      // 640 / 32 k-steps
#define BSW_PER_LAYER (KB_TOT * 8 * 64 * 8) // 81920 bf16 elems = 160 KB
#define BIN_SHIFT 12                   // 4096 segs per bin
#define BIN_SEGS 4096
#define NBINS 98                       // ceil(400000/4096)
#define EPB 2048                       // edges per bin_scatter block

typedef __attribute__((ext_vector_type(8))) short bfrag; // 8 bf16 (4 VGPR)
typedef __attribute__((ext_vector_type(4))) float ffrag; // 4 f32 acc

__device__ __forceinline__ unsigned short f2bf(float f) {
    unsigned u = __float_as_uint(f);
    u += 0x7fffu + ((u >> 16) & 1u); // RNE
    return (unsigned short)(u >> 16);
}
__device__ __forceinline__ float bf_lo(unsigned u) { return __uint_as_float(u << 16); }
__device__ __forceinline__ float bf_hi(unsigned u) { return __uint_as_float(u & 0xffff0000u); }

// ---------- cast x (f32) -> bf16 sidecar ----------
__global__ __launch_bounds__(256) void cast_x(
    const float* __restrict__ x, unsigned short* __restrict__ xb)
{
    int i = blockIdx.x * 256 + threadIdx.x;
    float4 v = ((const float4*)x)[i];
    ushort4 o = { f2bf(v.x), f2bf(v.y), f2bf(v.z), f2bf(v.w) };
    ((ushort4*)xb)[i] = o;
}

// ---------- pre-swizzle weights into MFMA B-fragment order ----------
__global__ __launch_bounds__(256) void prep_weights(
    const float* __restrict__ W,    // [L,4,128,128]
    const float* __restrict__ root, // [L,128,128]
    unsigned short* __restrict__ Bsw)
{
    int idx = blockIdx.x * 256 + threadIdx.x;
    int layer = idx / BSW_PER_LAYER;
    int rem = idx % BSW_PER_LAYER;
    int kb = rem / 4096;
    int rem2 = rem % 4096;
    int ct = rem2 / 512;
    int rem3 = rem2 % 512;
    int lane = rem3 / 8;
    int j = rem3 % 8;
    int k = kb * 32 + (lane >> 4) * 8 + j;
    int n = ct * 16 + (lane & 15);
    float v;
    if (k < 512) v = W[(size_t)layer * 4 * 128 * 128 + (size_t)k * 128 + n];
    else         v = root[(size_t)layer * 128 * 128 + (size_t)(k - 512) * 128 + n];
    Bsw[idx] = f2bf(v);
}

// ---------- CSR build: counts + scan (verbatim) ----------
__global__ __launch_bounds__(256) void count_edges(
    const int* __restrict__ dst, const int* __restrict__ et,
    int* __restrict__ counts)
{
    int e = blockIdx.x * 256 + threadIdx.x;
    if (e < NEDGE) atomicAdd(&counts[dst[e] * RREL + et[e]], 1);
}

__global__ __launch_bounds__(256) void scan_blocks(
    const int* __restrict__ counts, int* __restrict__ cursor,
    int* __restrict__ blockSums)
{
    __shared__ int waveTot[4];
    int base = blockIdx.x * 1024 + threadIdx.x * 4;
    int v[4];
    #pragma unroll
    for (int i = 0; i < 4; ++i) {
        int idx = base + i;
        v[i] = (idx < NSEG) ? counts[idx] : 0;
    }
    int tsum = v[0] + v[1] + v[2] + v[3];
    int lane = threadIdx.x & 63;
    int wave = threadIdx.x >> 6;
    int inc = tsum;
    #pragma unroll
    for (int d = 1; d < 64; d <<= 1) {
        int o = __shfl_up(inc, d, 64);
        if (lane >= d) inc += o;
    }
    if (lane == 63) waveTot[wave] = inc;
    __syncthreads();
    int wbase = 0;
    for (int w = 0; w < wave; ++w) wbase += waveTot[w];
    int run = wbase + inc - tsum;
    #pragma unroll
    for (int i = 0; i < 4; ++i) {
        int idx = base + i;
        if (idx < NSEG) cursor[idx] = run;
        run += v[i];
    }
    if (threadIdx.x == 255) blockSums[blockIdx.x] = wbase + inc;
}

__global__ __launch_bounds__(512) void scan_partials(int* __restrict__ blockSums)
{
    __shared__ int sm[512];
    int t = threadIdx.x;
    int v = (t < SCAN_NB) ? blockSums[t] : 0;
    sm[t] = v;
    __syncthreads();
    for (int d = 1; d < 512; d <<= 1) {
        int o = (t >= d) ? sm[t - d] : 0;
        __syncthreads();
        sm[t] += o;
        __syncthreads();
    }
    if (t < SCAN_NB) blockSums[t] = sm[t] - v;
}

__global__ __launch_bounds__(256) void scan_add(
    int* __restrict__ cursor, const int* __restrict__ blockSums)
{
    int base = blockIdx.x * 1024 + threadIdx.x * 4;
    int add = blockSums[blockIdx.x];
    #pragma unroll
    for (int i = 0; i < 4; ++i)
        if (base + i < NSEG) cursor[base + i] += add;
}

// ---------- binned fill, pass 0: snapshot bin bases from scanned cursor ----------
__global__ __launch_bounds__(128) void init_bins(
    const int* __restrict__ cursor, int* __restrict__ binCursor)
{
    int b = threadIdx.x;
    if (b < NBINS) {
        int sgi = b << BIN_SHIFT;
        binCursor[b] = (sgi < NSEG) ? cursor[sgi] : NEDGE;
    }
}

// ---------- binned fill, pass 1: chunk-reserved coalesced pair scatter ----------
// 782 blocks x 2048 edges: LDS histogram by bin, one global atomicAdd per
// non-empty bin reserves a contiguous chunk in pairs[], then write (src,seg).
__global__ __launch_bounds__(256) void bin_scatter(
    const int* __restrict__ src, const int* __restrict__ dst,
    const int* __restrict__ et, int* __restrict__ binCursor,
    uint2* __restrict__ pairs)
{
    __shared__ int hist[NBINS];
    __shared__ int base[NBINS];
    int tid = threadIdx.x;
    for (int b = tid; b < NBINS; b += 256) hist[b] = 0;
    __syncthreads();
    int e0 = blockIdx.x * EPB;
    #pragma unroll
    for (int i = 0; i < EPB / 256; ++i) {
        int e = e0 + i * 256 + tid;
        if (e < NEDGE) atomicAdd(&hist[(dst[e] * RREL + et[e]) >> BIN_SHIFT], 1);
    }
    __syncthreads();
    for (int b = tid; b < NBINS; b += 256) {
        int h = hist[b];
        base[b] = h ? atomicAdd(&binCursor[b], h) : 0;
        hist[b] = 0; // reuse as local arrival cursor
    }
    __syncthreads();
    #pragma unroll
    for (int i = 0; i < EPB / 256; ++i) {
        int e = e0 + i * 256 + tid;
        if (e < NEDGE) {
            int seg = dst[e] * RREL + et[e];
            int b = seg >> BIN_SHIFT;
            int li = atomicAdd(&hist[b], 1);
            pairs[base[b] + li] = make_uint2((unsigned)src[e], (unsigned)seg);
        }
    }
}

// ---------- binned fill, pass 2: per-bin placement via LDS cursors ----------
// One 1024-thread block per bin. Stage the bin's 4096 segment cursors into
// LDS; place each pair at ldsCur[seg]++ (LDS atomic); esrc writes confined to
// this block's 64KB region -> full-line assembly in its own L2. Global cursor
// is never mutated (aggregate is start-based).
__global__ __launch_bounds__(1024) void bin_fill(
    const uint2* __restrict__ pairs, const int* __restrict__ binStart,
    const int* __restrict__ binEnd, const int* __restrict__ cursor,
    int* __restrict__ esrc)
{
    __shared__ int ldsCur[BIN_SEGS];
    int b = blockIdx.x;
    int seg0 = b << BIN_SHIFT;
    for (int i = threadIdx.x; i < BIN_SEGS; i += 1024) {
        int sg = seg0 + i;
        if (sg < NSEG) ldsCur[i] = cursor[sg];
    }
    __syncthreads();
    int s = binStart[b], e = binEnd[b];
    for (int i = s + threadIdx.x; i < e; i += 1024) {
        uint2 p = pairs[i];
        int pos = atomicAdd(&ldsCur[p.y - (unsigned)seg0], 1);
        esrc[pos] = (int)p.x;
    }
}

// ---------- per-segment gather-reduce, 16 lanes/segment, start-based ----------
__global__ __launch_bounds__(256) void rgcn_aggregate(
    const unsigned short* __restrict__ xb, const int* __restrict__ esrc,
    const int* __restrict__ cursor, const int* __restrict__ counts,
    unsigned short* __restrict__ meanb)
{
    int sub = threadIdx.x >> 4;
    int lane16 = threadIdx.x & 15;
    int seg = blockIdx.x * 16 + sub;
    int j = cursor[seg];        // segment start (cursor is read-only now)
    int c = counts[seg];
    int end = j + c;
    float acc[8] = {};
    for (; j + 1 < end; j += 2) {
        int s0 = esrc[j], s1 = esrc[j + 1];
        uint4 u0 = ((const uint4*)(xb + (size_t)s0 * FDIM))[lane16];
        uint4 u1 = ((const uint4*)(xb + (size_t)s1 * FDIM))[lane16];
        acc[0] += bf_lo(u0.x) + bf_lo(u1.x);
        acc[1] += bf_hi(u0.x) + bf_hi(u1.x);
        acc[2] += bf_lo(u0.y) + bf_lo(u1.y);
        acc[3] += bf_hi(u0.y) + bf_hi(u1.y);
        acc[4] += bf_lo(u0.z) + bf_lo(u1.z);
        acc[5] += bf_hi(u0.z) + bf_hi(u1.z);
        acc[6] += bf_lo(u0.w) + bf_lo(u1.w);
        acc[7] += bf_hi(u0.w) + bf_hi(u1.w);
    }
    if (j < end) {
        int sv = esrc[j];
        uint4 u = ((const uint4*)(xb + (size_t)sv * FDIM))[lane16];
        acc[0] += bf_lo(u.x); acc[1] += bf_hi(u.x);
        acc[2] += bf_lo(u.y); acc[3] += bf_hi(u.y);
        acc[4] += bf_lo(u.z); acc[5] += bf_hi(u.z);
        acc[6] += bf_lo(u.w); acc[7] += bf_hi(u.w);
    }
    float inv = 1.0f / fmaxf((float)c, 1.0f);
    uint4 o;
    o.x = (unsigned)f2bf(acc[0] * inv) | ((unsigned)f2bf(acc[1] * inv) << 16);
    o.y = (unsigned)f2bf(acc[2] * inv) | ((unsigned)f2bf(acc[3] * inv) << 16);
    o.z = (unsigned)f2bf(acc[4] * inv) | ((unsigned)f2bf(acc[5] * inv) << 16);
    o.w = (unsigned)f2bf(acc[6] * inv) | ((unsigned)f2bf(acc[7] * inv) << 16);
    ((uint4*)(meanb + (size_t)seg * FDIM))[lane16] = o;
}

// ---------- MFMA transform (verbatim R8) ----------
__global__ __launch_bounds__(256, 2) void rgcn_transform(
    const unsigned short* __restrict__ xb,    // [N,128] bf16 activations
    const unsigned short* __restrict__ meanb, // [N,512] bf16
    const unsigned short* __restrict__ Bsw,   // this layer's [20][8][64][8]
    const float* __restrict__ bias,           // [128]
    float* __restrict__ out,                  // [N,128] f32 (live iff writeF32)
    unsigned short* __restrict__ xbn,         // [N,128] bf16 (live iff !writeF32)
    const int writeF32)
{
    __shared__ __align__(16) unsigned char Bsm[2][8192];

    int tid = threadIdx.x;
    int wave = tid >> 6, lane = tid & 63;
    int quad = lane >> 4, rlo = lane & 15;
    int n0 = blockIdx.x * 128 + wave * 32;
    int r0 = n0 + rlo;
    int r1 = n0 + 16 + rlo;
    int r0c = min(r0, N_NODES - 1);
    int r1c = min(r1, N_NODES - 1);

    const bfrag* m0 = (const bfrag*)(meanb + (size_t)r0c * 512) + quad;
    const bfrag* m1 = (const bfrag*)(meanb + (size_t)r1c * 512) + quad;
    const bfrag* x0 = (const bfrag*)(xb + (size_t)r0c * FDIM) + quad;
    const bfrag* x1 = (const bfrag*)(xb + (size_t)r1c * FDIM) + quad;

    const uint4* gB = (const uint4*)Bsw;
    #define STAGE_B(kb, buf) do { \
        uint4* _s = (uint4*)Bsm[buf]; \
        const uint4* _g = gB + (kb) * 512; \
        _s[tid] = _g[tid]; \
        _s[tid + 256] = _g[tid + 256]; \
    } while (0)

    #define AFRAG(row, kb) ((kb) < 16 ? row##_m[(kb) * 4] : row##_x[((kb) - 16) * 4])
    const bfrag* r0_m = m0; const bfrag* r0_x = x0;
    const bfrag* r1_m = m1; const bfrag* r1_x = x1;

    ffrag acc[2][8] = {};

    STAGE_B(0, 0);
    bfrag a0p0 = AFRAG(r0, 0), a1p0 = AFRAG(r1, 0);
    bfrag a0p1 = AFRAG(r0, 1), a1p1 = AFRAG(r1, 1);
    __syncthreads();

    #pragma unroll
    for (int kb = 0; kb < KB_TOT; ++kb) {
        int cur = kb & 1;
        if (kb + 1 < KB_TOT) STAGE_B(kb + 1, cur ^ 1);

        bfrag a0 = cur ? a0p1 : a0p0;
        bfrag a1 = cur ? a1p1 : a1p0;
        if (kb + 2 < KB_TOT) {
            if (cur) { a0p1 = AFRAG(r0, kb + 2); a1p1 = AFRAG(r1, kb + 2); }
            else     { a0p0 = AFRAG(r0, kb + 2); a1p0 = AFRAG(r1, kb + 2); }
        }

        #pragma unroll
        for (int ct = 0; ct < 8; ++ct) {
            bfrag b = *(const bfrag*)&Bsm[cur][ct * 1024 + lane * 16];
            acc[0][ct] = __builtin_amdgcn_mfma_f32_16x16x32_bf16(a0, b, acc[0][ct], 0, 0, 0);
            acc[1][ct] = __builtin_amdgcn_mfma_f32_16x16x32_bf16(a1, b, acc[1][ct], 0, 0, 0);
        }
        __syncthreads();
    }
    #undef STAGE_B
    #undef AFRAG

    float bcol[8];
    #pragma unroll
    for (int ct = 0; ct < 8; ++ct) bcol[ct] = bias[ct * 16 + rlo];

    #pragma unroll
    for (int rt = 0; rt < 2; ++rt) {
        int rbase = n0 + rt * 16 + quad * 4;
        #pragma unroll
        for (int i = 0; i < 4; ++i) {
            int r = rbase + i;
            if (r < N_NODES) {
                #pragma unroll
                for (int ct = 0; ct < 8; ++ct) {
                    float v = fmaxf(acc[rt][ct][i] + bcol[ct], 0.0f);
                    int col = ct * 16 + rlo;
                    if (writeF32) out[(size_t)r * FDIM + col] = v;
                    else          xbn[(size_t)r * FDIM + col] = f2bf(v);
                }
            }
        }
    }
}

extern "C" void kernel_launch(void* const* d_in, const int* in_sizes, int n_in,
                              void* d_out, int out_size, void* d_ws, size_t ws_size,
                              hipStream_t stream) {
    const float* x        = (const float*)d_in[0];
    const int* edge_index = (const int*)d_in[1]; // [2,E]
    const int* edge_type  = (const int*)d_in[2]; // [E]
    const float* weights  = (const float*)d_in[3]; // [L,R,F,F]
    const float* roots    = (const float*)d_in[4]; // [L,F,F]
    const float* biases   = (const float*)d_in[5]; // [L,F]
    float* out = (float*)d_out;

    // workspace layout
    unsigned short* meanb = (unsigned short*)d_ws;            // NSEG*128 bf16 = 102.4 MB
    unsigned short* xb0   = meanb + (size_t)NSEG * FDIM;      // N*128 bf16
    unsigned short* xb1   = xb0 + (size_t)N_NODES * FDIM;     // N*128 bf16
    unsigned short* Bsw   = xb1 + (size_t)N_NODES * FDIM;     // 2*81920 bf16
    int* esrc   = (int*)(Bsw + 2 * BSW_PER_LAYER);            // E ints
    int* counts = esrc + NEDGE;                               // NSEG
    int* cursor = counts + NSEG;                              // NSEG
    int* blockSums = cursor + NSEG;                           // 512
    int* binCursor = blockSums + 512;                         // NBINS
    int* binStart  = binCursor + NBINS;                       // NBINS
    uint2* pairs = (uint2*)(((size_t)(binStart + NBINS) + 15) & ~(size_t)15); // E uint2

    const int* src = edge_index;
    const int* dst = edge_index + NEDGE;

    // prep: bf16 cast + weight swizzle + CSR counts/scan (edges layer-invariant)
    cast_x<<<(N_NODES * FDIM / 4) / 256, 256, 0, stream>>>(x, xb0);
    prep_weights<<<2 * BSW_PER_LAYER / 256, 256, 0, stream>>>(weights, roots, Bsw);
    hipMemsetAsync(counts, 0, NSEG * sizeof(int), stream);
    count_edges<<<NEDGE / 256, 256, 0, stream>>>(dst, edge_type, counts);
    scan_blocks<<<SCAN_NB, 256, 0, stream>>>(counts, cursor, blockSums);
    scan_partials<<<1, 512, 0, stream>>>(blockSums);
    scan_add<<<SCAN_NB, 256, 0, stream>>>(cursor, blockSums);
    // binned two-pass fill: snapshot starts, reserve chunks, place via LDS
    init_bins<<<1, 128, 0, stream>>>(cursor, binStart);
    hipMemcpyAsync(binCursor, binStart, NBINS * sizeof(int),
                   hipMemcpyDeviceToDevice, stream);
    bin_scatter<<<(NEDGE + EPB - 1) / EPB, 256, 0, stream>>>(src, dst, edge_type,
                                                             binCursor, pairs);
    bin_fill<<<NBINS, 1024, 0, stream>>>(pairs, binStart, binCursor, cursor, esrc);

    const int tgrid = (N_NODES + 127) / 128; // 782

    // layer 1: bf16 sidecar only
    rgcn_aggregate<<<NSEG / 16, 256, 0, stream>>>(xb0, esrc, cursor, counts, meanb);
    rgcn_transform<<<tgrid, 256, 0, stream>>>(xb0, meanb, Bsw, biases, out, xb1, 0);
    // layer 2: f32 output only
    rgcn_aggregate<<<NSEG / 16, 256, 0, stream>>>(xb1, esrc, cursor, counts, meanb);
    rgcn_transform<<<tgrid, 256, 0, stream>>>(xb1, meanb, Bsw + BSW_PER_LAYER,
                                              biases + FDIM, out, xb0, 1);
}